// Round 4
// baseline (114.422 us; speedup 1.0000x reference)
//
#include <hip/hip_runtime.h>
#include <math.h>

// Problem constants (match reference)
constexpr int V = 131072;   // vocab / leaves
constexpr int D = 17;       // tree depth
constexpr int B = 16384;    // batch
constexpr int E = 128;      // embedding dim

constexpr int LPG  = 16;                  // lanes per sample group
constexpr int SPB  = 16;                  // samples per block (256 threads / 16)
constexpr int NGRP = B / SPB;             // 1024 sample-groups
constexpr int NBLK = NGRP * 2;            // 2048 blocks: even=levels 0-8, odd=9-16

// 16 lanes per sample, 4 samples per wave, embedding register-cached.
// Tree levels are SPLIT across two blocks per sample-group: this doubles the
// resident wave count (8192 waves -> 8/SIMD, full occupancy) and halves each
// wave's serial load->shuffle critical path. The kernel is latency-bound,
// not BW-bound (VALU ~1.4us, VMEM issue ~1.4us, HBM-unique ~6us vs 17us seen).
template<int D0, int D1>
__device__ __forceinline__ float levels_loss(
    const float4 e0, const float4 e1, const int j0, const int l,
    const float* __restrict__ W, const float* __restrict__ bias)
{
    float loss = 0.0f;
    #pragma unroll
    for (int d = D0; d < D1; ++d) {
        const int   jc   = j0 >> d;        // 1-indexed child at this step
        const int   node = (jc >> 1) - 1;  // 0-indexed parent (scored node)
        const float t    = (float)(1 - (jc & 1));

        const float4* wr = (const float4*)(W + (size_t)node * E);
        const float4 w0 = wr[l];
        const float4 w1 = wr[l + LPG];

        float p;
        p = fmaf(e0.x, w0.x, e0.y * w0.y);
        p = fmaf(e0.z, w0.z, p);
        p = fmaf(e0.w, w0.w, p);
        p = fmaf(e1.x, w1.x, p);
        p = fmaf(e1.y, w1.y, p);
        p = fmaf(e1.z, w1.z, p);
        p = fmaf(e1.w, w1.w, p);

        // reduce across the 16 lanes of the subgroup
        p += __shfl_xor(p, 1, 64);
        p += __shfl_xor(p, 2, 64);
        p += __shfl_xor(p, 4, 64);
        p += __shfl_xor(p, 8, 64);

        const float s = p + bias[node];
        loss += fmaxf(s, 0.0f) - s * t + __logf(1.0f + __expf(-fabsf(s)));
    }
    return loss;
}

__global__ __launch_bounds__(256) void hsm_main(
    const float* __restrict__ emb,
    const int*   __restrict__ widx,
    const float* __restrict__ W,
    const float* __restrict__ bias,
    float*       __restrict__ partial)
{
    const int lane = threadIdx.x & 63;
    const int wid  = threadIdx.x >> 6;
    const int g    = lane >> 4;            // subgroup 0..3 within wave
    const int l    = lane & 15;            // lane within subgroup
    const int grp  = blockIdx.x >> 1;      // sample-group id
    const int half = blockIdx.x & 1;       // 0: levels 0-8, 1: levels 9-16
    const int b    = grp * SPB + wid * 4 + g;

    // embedding row: 16 lanes x 2 float4 = 512 B, register-cached
    const float4* er = (const float4*)(emb + (size_t)b * E);
    const float4 e0 = er[l];
    const float4 e1 = er[l + LPG];

    const int j0 = widx[b] + V;            // 1-indexed leaf in heap layout

    float loss = half ? levels_loss<9, 17>(e0, e1, j0, l, W, bias)
                      : levels_loss<0,  9>(e0, e1, j0, l, W, bias);

    // combine the 4 subgroups of the wave
    loss += __shfl_xor(loss, 16, 64);
    loss += __shfl_xor(loss, 32, 64);

    __shared__ float red[4];
    if (lane == 0) red[wid] = loss;
    __syncthreads();
    if (threadIdx.x == 0)
        partial[blockIdx.x] = (red[0] + red[1]) + (red[2] + red[3]);
}

__global__ __launch_bounds__(256) void hsm_reduce(
    const float* __restrict__ partial,
    float*       __restrict__ out)
{
    float s = 0.0f;
    for (int i = threadIdx.x; i < NBLK; i += 256) s += partial[i];
    #pragma unroll
    for (int off = 32; off >= 1; off >>= 1)
        s += __shfl_xor(s, off, 64);

    __shared__ float red[4];
    const int lane = threadIdx.x & 63, wid = threadIdx.x >> 6;
    if (lane == 0) red[wid] = s;
    __syncthreads();
    if (threadIdx.x == 0)
        out[0] = ((red[0] + red[1]) + (red[2] + red[3])) * (1.0f / (float)B);
}

extern "C" void kernel_launch(void* const* d_in, const int* in_sizes, int n_in,
                              void* d_out, int out_size, void* d_ws, size_t ws_size,
                              hipStream_t stream) {
    const float* emb  = (const float*)d_in[0];   // [B,E] f32
    const int*   widx = (const int*)  d_in[1];   // [B]   i32
    const float* W    = (const float*)d_in[2];   // [V-1,E] f32
    const float* bias = (const float*)d_in[3];   // [V-1] f32
    float* out     = (float*)d_out;
    float* partial = (float*)d_ws;               // NBLK floats, fully overwritten

    hsm_main<<<NBLK, 256, 0, stream>>>(emb, widx, W, bias, partial);
    hsm_reduce<<<1, 256, 0, stream>>>(partial, out);
}

// Round 5
// 111.895 us; speedup vs baseline: 1.0226x; 1.0226x over previous
//
#include <hip/hip_runtime.h>
#include <math.h>

// Problem constants (match reference)
constexpr int V = 131072;   // vocab / leaves
constexpr int D = 17;       // tree depth
constexpr int B = 16384;    // batch
constexpr int E = 128;      // embedding dim

constexpr int LPG  = 16;                  // lanes per sample group
constexpr int SPB  = 16;                  // samples per block (256 threads / 16)
constexpr int NBLK = B / SPB;             // 1024 blocks

// 16 lanes per sample, 4 samples per wave, embedding register-cached.
// R5 restructure: batch the pipeline to break R3's serial per-level chain.
//   phase 1: 17 per-lane partial dots (34 independent global loads -> deep
//            vmcnt batching, 17 independent FMA chains)
//   phase 2: 4 butterfly stages over ALL 17 values (17-wide ILP per stage)
//   phase 3: 17 BCEs (independent), every lane already holds full sums
// __launch_bounds__(256,4) caps VGPR at 128 so the grid's 4 waves/SIMD fit.
__global__ __launch_bounds__(256, 4) void hsm_main(
    const float* __restrict__ emb,
    const int*   __restrict__ widx,
    const float* __restrict__ W,
    const float* __restrict__ bias,
    float*       __restrict__ partial)
{
    const int lane = threadIdx.x & 63;
    const int wid  = threadIdx.x >> 6;
    const int g    = lane >> 4;            // subgroup 0..3 within wave
    const int l    = lane & 15;            // lane within subgroup
    const int b    = blockIdx.x * SPB + wid * 4 + g;

    // embedding row: 16 lanes x 2 float4 = 512 B, register-cached
    const float4* er = (const float4*)(emb + (size_t)b * E);
    const float4 e0 = er[l];
    const float4 e1 = er[l + LPG];

    const int j0 = widx[b] + V;            // 1-indexed leaf in heap layout

    // phase 1: per-lane partial dot for every level (all loads independent)
    float p[D];
    #pragma unroll
    for (int d = 0; d < D; ++d) {
        const int node = ((j0 >> d) >> 1) - 1;
        const float4* wr = (const float4*)(W + (size_t)node * E);
        const float4 w0 = wr[l];
        const float4 w1 = wr[l + LPG];
        float a = fmaf(e0.x, w0.x, e0.y * w0.y);
        float c = fmaf(e0.z, w0.z, e0.w * w0.w);
        a = fmaf(e1.x, w1.x, a);
        c = fmaf(e1.y, w1.y, c);
        a = fmaf(e1.z, w1.z, a);
        c = fmaf(e1.w, w1.w, c);
        p[d] = a + c;
    }

    // phase 2: batched butterfly across the 16-lane subgroup (17-wide ILP)
    #pragma unroll
    for (int off = 1; off <= 8; off <<= 1) {
        #pragma unroll
        for (int d = 0; d < D; ++d)
            p[d] += __shfl_xor(p[d], off, 64);
    }

    // phase 3: bias + stable BCE-with-logits per level (all independent);
    // every lane of the subgroup holds identical full sums now.
    float loss = 0.0f;
    #pragma unroll
    for (int d = 0; d < D; ++d) {
        const int   jc   = j0 >> d;
        const int   node = (jc >> 1) - 1;
        const float t    = (float)(1 - (jc & 1));
        const float s    = p[d] + bias[node];
        loss += fmaxf(s, 0.0f) - s * t + __logf(1.0f + __expf(-fabsf(s)));
    }

    // combine the 4 subgroups of the wave (values uniform within subgroup)
    loss += __shfl_xor(loss, 16, 64);
    loss += __shfl_xor(loss, 32, 64);

    __shared__ float red[4];
    if (lane == 0) red[wid] = loss;
    __syncthreads();
    if (threadIdx.x == 0)
        partial[blockIdx.x] = (red[0] + red[1]) + (red[2] + red[3]);
}

__global__ __launch_bounds__(256) void hsm_reduce(
    const float* __restrict__ partial,
    float*       __restrict__ out)
{
    float s = 0.0f;
    for (int i = threadIdx.x; i < NBLK; i += 256) s += partial[i];
    #pragma unroll
    for (int off = 32; off >= 1; off >>= 1)
        s += __shfl_xor(s, off, 64);

    __shared__ float red[4];
    const int lane = threadIdx.x & 63, wid = threadIdx.x >> 6;
    if (lane == 0) red[wid] = s;
    __syncthreads();
    if (threadIdx.x == 0)
        out[0] = ((red[0] + red[1]) + (red[2] + red[3])) * (1.0f / (float)B);
}

extern "C" void kernel_launch(void* const* d_in, const int* in_sizes, int n_in,
                              void* d_out, int out_size, void* d_ws, size_t ws_size,
                              hipStream_t stream) {
    const float* emb  = (const float*)d_in[0];   // [B,E] f32
    const int*   widx = (const int*)  d_in[1];   // [B]   i32
    const float* W    = (const float*)d_in[2];   // [V-1,E] f32
    const float* bias = (const float*)d_in[3];   // [V-1] f32
    float* out     = (float*)d_out;
    float* partial = (float*)d_ws;               // NBLK floats, fully overwritten

    hsm_main<<<NBLK, 256, 0, stream>>>(emb, widx, W, bias, partial);
    hsm_reduce<<<1, 256, 0, stream>>>(partial, out);
}